// Round 5
// baseline (2751.749 us; speedup 1.0000x reference)
//
#include <hip/hip_runtime.h>

typedef unsigned short u16;
typedef __attribute__((ext_vector_type(8))) short bf16x8;
typedef __attribute__((ext_vector_type(4))) float f32x4;

// ---- bf16 helpers (RNE) ----
__device__ inline float bf2f(u16 u) {
    unsigned v = ((unsigned)u) << 16;
    return __builtin_bit_cast(float, v);
}
__device__ inline u16 f2bf(float f) {
    unsigned u = __builtin_bit_cast(unsigned, f);
    u += 0x7fff + ((u >> 16) & 1);
    return (u16)(u >> 16);
}

// ============================================================
// Dtype detector (fp32 vs bf16 device buffers). flag=1 -> fp32.
// ============================================================
__global__ void detect_kernel(const u16* __restrict__ xr, int* __restrict__ flag) {
    __shared__ int red[4];
    const int t = threadIdx.x;
    int cnt = 0;
    for (int j = 0; j < 64; ++j) {
        u16 v = xr[(t * 64 + j) * 2];
        int e = (v >> 7) & 0xFF;
        cnt += (e >= 0x86);
    }
    for (int o = 32; o >= 1; o >>= 1) cnt += __shfl_xor(cnt, o);
    if ((t & 63) == 0) red[t >> 6] = cnt;
    __syncthreads();
    if (t == 0) flag[0] = ((red[0] + red[1] + red[2] + red[3]) > 1000) ? 1 : 0;
}

// ============================================================
// Weight transpose + convert-to-bf16: dst[C][R] = bf16(src[R][C])
// ============================================================
__global__ __launch_bounds__(256) void transpose_kernel(const float* __restrict__ srcf,
                                                        const u16* __restrict__ srch,
                                                        u16* __restrict__ dst,
                                                        int R, int C,
                                                        const int* __restrict__ flag) {
    __shared__ u16 tile[64][65];
    const bool isf32 = flag[0] != 0;
    const int t = threadIdx.x;
    const int c0 = blockIdx.x * 64, r0 = blockIdx.y * 64;
    const int lc = t & 63, lr4 = t >> 6;
#pragma unroll
    for (int i = 0; i < 16; ++i) {
        int row = i * 4 + lr4;
        size_t idx = (size_t)(r0 + row) * C + c0 + lc;
        tile[row][lc] = isf32 ? f2bf(srcf[idx]) : srch[idx];
    }
    __syncthreads();
#pragma unroll
    for (int i = 0; i < 16; ++i) {
        int drow = i * 4 + lr4;
        dst[(size_t)(c0 + drow) * R + r0 + lc] = tile[lc][drow];
    }
}

// ============================================================
// bf16 transpose (per batch z): dst[b][C][R] = src[b][R][C], R=C=1024
// ============================================================
__global__ __launch_bounds__(256) void transpose_bf16_kernel(const u16* __restrict__ src,
                                                             u16* __restrict__ dst) {
    __shared__ u16 tile[64][65];
    const int t = threadIdx.x;
    const int c0 = blockIdx.x * 64, r0 = blockIdx.y * 64;
    const size_t boff = (size_t)blockIdx.z * 1024 * 1024;
    src += boff;
    dst += boff;
    const int lc = t & 63, lr4 = t >> 6;
#pragma unroll
    for (int i = 0; i < 16; ++i) {
        int row = i * 4 + lr4;
        tile[row][lc] = src[(size_t)(r0 + row) * 1024 + c0 + lc];
    }
    __syncthreads();
#pragma unroll
    for (int i = 0; i < 16; ++i) {
        int drow = i * 4 + lr4;
        dst[(size_t)(c0 + drow) * 1024 + r0 + lc] = tile[lc][drow];
    }
}

// ============================================================
// GEMM1: proj[65536][1024] = bf16(x)[65536][512] @ W1 + bias1, bf16 out
// ============================================================
__global__ __launch_bounds__(256) void gemm1_kernel(const float* __restrict__ xf,
                                                    const u16* __restrict__ xh,
                                                    const u16* __restrict__ w1t,
                                                    const float* __restrict__ b1f,
                                                    const u16* __restrict__ b1h,
                                                    u16* __restrict__ proj,
                                                    const int* __restrict__ flag) {
    __shared__ u16 Al[128 * 64];
    __shared__ u16 Bl[128 * 64];
    const bool isf32 = flag[0] != 0;
    const int t = threadIdx.x;
    const int lane = t & 63;
    const int w = t >> 6;
    const int r0 = blockIdx.y * 128;
    const int c0 = blockIdx.x * 128;
    const int wr = (w >> 1) * 64, wc = (w & 1) * 64;

    f32x4 acc[4][4] = {};

    for (int kt = 0; kt < 8; ++kt) {
        const int k0 = kt * 64;
#pragma unroll
        for (int i = 0; i < 4; ++i) {
            int c = i * 256 + t;
            int row = c >> 3;
            int off = (c & 7) * 8;
            size_t gidx = (size_t)(r0 + row) * 512 + k0 + off;
            bf16x8 av;
            if (isf32) {
                f32x4 f0 = *(const f32x4*)&xf[gidx];
                f32x4 f1 = *(const f32x4*)&xf[gidx + 4];
#pragma unroll
                for (int j = 0; j < 4; ++j) {
                    av[j] = (short)f2bf(f0[j]);
                    av[j + 4] = (short)f2bf(f1[j]);
                }
            } else {
                av = *(const bf16x8*)&xh[gidx];
            }
            *(bf16x8*)&Al[row * 64 + off] = av;
            *(bf16x8*)&Bl[row * 64 + off] =
                *(const bf16x8*)&w1t[(size_t)(c0 + row) * 512 + k0 + off];
        }
        __syncthreads();
#pragma unroll
        for (int kk = 0; kk < 64; kk += 32) {
            bf16x8 a[4], bb[4];
#pragma unroll
            for (int m = 0; m < 4; ++m)
                a[m] = *(const bf16x8*)&Al[(wr + m * 16 + (lane & 15)) * 64 + kk + (lane >> 4) * 8];
#pragma unroll
            for (int n = 0; n < 4; ++n)
                bb[n] = *(const bf16x8*)&Bl[(wc + n * 16 + (lane & 15)) * 64 + kk + (lane >> 4) * 8];
#pragma unroll
            for (int m = 0; m < 4; ++m)
#pragma unroll
                for (int n = 0; n < 4; ++n)
                    acc[m][n] = __builtin_amdgcn_mfma_f32_16x16x32_bf16(a[m], bb[n], acc[m][n], 0, 0, 0);
        }
        __syncthreads();
    }

#pragma unroll
    for (int n = 0; n < 4; ++n) {
        int col = c0 + wc + n * 16 + (lane & 15);
        float bv = isf32 ? b1f[col] : bf2f(b1h[col]);
#pragma unroll
        for (int m = 0; m < 4; ++m) {
            int rbase = r0 + wr + m * 16 + (lane >> 4) * 4;
#pragma unroll
            for (int i = 0; i < 4; ++i)
                proj[(size_t)(rbase + i) * 1024 + col] = f2bf(acc[m][n][i] + bv);
        }
    }
}

// ============================================================
// Fused attention per wg = (batch b, 16 query rows). 512 thr = 8 waves.
// PT=true: V-fragments are 16B vector loads from projT (e-major).
// PT=false: scalar-gather fallback from row-major proj.
// ============================================================
template <bool PT>
__global__ __launch_bounds__(512) void attn_kernel(const u16* __restrict__ proj,
                                                   const u16* __restrict__ projT,
                                                   const u16* __restrict__ w2t,
                                                   const float* __restrict__ b2f,
                                                   const u16* __restrict__ b2h,
                                                   float* __restrict__ outf,
                                                   u16* __restrict__ outh,
                                                   const int* __restrict__ flag) {
    __shared__ u16 Pl[16 * 1032];      // P (stride 1024 u16, swizzled) then O (stride 1032)
    __shared__ float mred[16][8];
    __shared__ float sred[16][8];
    const bool isf32 = flag[0] != 0;
    const int t = threadIdx.x;
    const int lane = t & 63;
    const int w = t >> 6;
    const int b = blockIdx.y;
    const int n0 = blockIdx.x * 16;
    const u16* pb = proj + (size_t)b * 1024 * 1024;
    const int g = lane >> 4;
    const int lr = lane & 15;

    // ---- Phase 1: S = Q @ relu(K)^T / 32, in registers
    f32x4 acc[8] = {};
    const int mw = w * 128;
    for (int kk = 0; kk < 1024; kk += 32) {
        const int e = kk + g * 8;
        bf16x8 a = *(const bf16x8*)&pb[(size_t)(n0 + lr) * 1024 + e];
        bf16x8 kf[8];
#pragma unroll
        for (int cf = 0; cf < 8; ++cf) {
            bf16x8 v = *(const bf16x8*)&pb[(size_t)(mw + cf * 16 + lr) * 1024 + e];
            v &= ~(v >> 15);   // bf16 relu
            kf[cf] = v;
        }
#pragma unroll
        for (int cf = 0; cf < 8; ++cf)
            acc[cf] = __builtin_amdgcn_mfma_f32_16x16x32_bf16(a, kf[cf], acc[cf], 0, 0, 0);
    }
    {
        const float sc = 1.0f / 32.0f;
#pragma unroll
        for (int cf = 0; cf < 8; ++cf)
#pragma unroll
            for (int i = 0; i < 4; ++i) acc[cf][i] *= sc;
    }

    // ---- Phase 2: softmax (rows ri=g*4+i live across 16 lr lanes x 8 cf)
    {
#pragma unroll
        for (int i = 0; i < 4; ++i) {
            float m = acc[0][i];
#pragma unroll
            for (int cf = 1; cf < 8; ++cf) m = fmaxf(m, acc[cf][i]);
            for (int o = 8; o >= 1; o >>= 1) m = fmaxf(m, __shfl_xor(m, o));
            if (lr == 0) mred[g * 4 + i][w] = m;
        }
    }
    __syncthreads();
    {
        float gm[4];
#pragma unroll
        for (int i = 0; i < 4; ++i) {
            int ri = g * 4 + i;
            float m = mred[ri][0];
#pragma unroll
            for (int w2 = 1; w2 < 8; ++w2) m = fmaxf(m, mred[ri][w2]);
            gm[i] = m;
        }
#pragma unroll
        for (int i = 0; i < 4; ++i) {
            float s = 0.f;
#pragma unroll
            for (int cf = 0; cf < 8; ++cf) {
                acc[cf][i] = __expf(acc[cf][i] - gm[i]);
                s += acc[cf][i];
            }
            for (int o = 8; o >= 1; o >>= 1) s += __shfl_xor(s, o);
            if (lr == 0) sred[g * 4 + i][w] = s;
        }
    }
    __syncthreads();
    {
        float inv[4];
#pragma unroll
        for (int i = 0; i < 4; ++i) {
            int ri = g * 4 + i;
            float s = sred[ri][0];
#pragma unroll
            for (int w2 = 1; w2 < 8; ++w2) s += sred[ri][w2];
            inv[i] = 1.0f / s;
        }
        char* Pb = (char*)Pl;
#pragma unroll
        for (int i = 0; i < 4; ++i) {
            int ri = g * 4 + i;
            int rx = (ri & 7) << 4;
            char* prow = Pb + ri * 2048;
#pragma unroll
            for (int cf = 0; cf < 8; ++cf) {
                int c = mw + cf * 16 + lr;
                *(u16*)(prow + ((2 * c) ^ rx)) = f2bf(acc[cf][i] * inv[i]);
            }
        }
    }
    __syncthreads();

    // ---- Phase 3: O = P @ V
    f32x4 acc2[8] = {};
    {
        const int ew = w * 128;
        const char* Pb = (const char*)Pl;
        const int rx = (lr & 7) << 4;
        if (PT) {
            const u16* ptb = projT + (size_t)b * 1024 * 1024;
            for (int m0 = 0; m0 < 1024; m0 += 32) {
                const int mq = m0 + g * 8;
                bf16x8 pa = *(const bf16x8*)(Pb + lr * 2048 + ((2 * mq) ^ rx));
#pragma unroll
                for (int cf = 0; cf < 8; ++cf) {
                    bf16x8 vv = *(const bf16x8*)&ptb[(size_t)(ew + cf * 16 + lr) * 1024 + mq];
                    acc2[cf] = __builtin_amdgcn_mfma_f32_16x16x32_bf16(pa, vv, acc2[cf], 0, 0, 0);
                }
            }
        } else {
            for (int m0 = 0; m0 < 1024; m0 += 32) {
                const int mq = m0 + g * 8;
                bf16x8 pa = *(const bf16x8*)(Pb + lr * 2048 + ((2 * mq) ^ rx));
#pragma unroll
                for (int cf = 0; cf < 8; ++cf) {
                    const u16* vp = &pb[(size_t)mq * 1024 + ew + cf * 16 + lr];
                    bf16x8 vv;
#pragma unroll
                    for (int j = 0; j < 8; ++j) vv[j] = (short)vp[(size_t)j * 1024];
                    acc2[cf] = __builtin_amdgcn_mfma_f32_16x16x32_bf16(pa, vv, acc2[cf], 0, 0, 0);
                }
            }
        }
    }
    __syncthreads();
    u16* Ol = Pl;
    {
        const int ew = w * 128;
#pragma unroll
        for (int cf = 0; cf < 8; ++cf)
#pragma unroll
            for (int i = 0; i < 4; ++i)
                Ol[(g * 4 + i) * 1032 + ew + cf * 16 + lr] = f2bf(acc2[cf][i]);
    }
    __syncthreads();

    // ---- Phase 4: out = relu(O @ W2 + bias2)
    {
        f32x4 acc3[4] = {};
        const int dw = w * 64;
        for (int kk = 0; kk < 1024; kk += 32) {
            const int e0 = kk + g * 8;
            bf16x8 oa = *(const bf16x8*)&Ol[lr * 1032 + e0];
            bf16x8 wb[4];
#pragma unroll
            for (int cf = 0; cf < 4; ++cf)
                wb[cf] = *(const bf16x8*)&w2t[(size_t)(dw + cf * 16 + lr) * 1024 + e0];
#pragma unroll
            for (int cf = 0; cf < 4; ++cf)
                acc3[cf] = __builtin_amdgcn_mfma_f32_16x16x32_bf16(oa, wb[cf], acc3[cf], 0, 0, 0);
        }
#pragma unroll
        for (int cf = 0; cf < 4; ++cf) {
            int d = dw + cf * 16 + lr;
            float bv = isf32 ? b2f[d] : bf2f(b2h[d]);
#pragma unroll
            for (int i = 0; i < 4; ++i) {
                float v = fmaxf(acc3[cf][i] + bv, 0.f);
                size_t oi = ((size_t)b * 1024 + n0 + g * 4 + i) * 512 + d;
                if (isf32) outf[oi] = v;
                else outh[oi] = f2bf(v);
            }
        }
    }
}

// ============================================================
// Launch. ws: [0,1MB) W1T | [1MB,2MB) W2T | [2MB,130MB) proj | flag @130MB
//         | projT @130MB+4KB (only if ws_size >= 258MB+8KB)
// ============================================================
extern "C" void kernel_launch(void* const* d_in, const int* in_sizes, int n_in,
                              void* d_out, int out_size, void* d_ws, size_t ws_size,
                              hipStream_t stream) {
    char* ws = (char*)d_ws;
    u16* W1T   = (u16*)ws;
    u16* W2T   = (u16*)(ws + (1u << 20));
    u16* proj  = (u16*)(ws + (2u << 20));
    int* flag  = (int*)(ws + ((size_t)130 << 20));
    u16* projT = (u16*)(ws + ((size_t)130 << 20) + 4096);
    const bool use_pt = ws_size >= (((size_t)258 << 20) + 8192);

    detect_kernel<<<1, 256, 0, stream>>>((const u16*)d_in[0], flag);

    transpose_kernel<<<dim3(16, 8, 1), 256, 0, stream>>>(
        (const float*)d_in[1], (const u16*)d_in[1], W1T, 512, 1024, flag);
    transpose_kernel<<<dim3(8, 16, 1), 256, 0, stream>>>(
        (const float*)d_in[3], (const u16*)d_in[3], W2T, 1024, 512, flag);

    gemm1_kernel<<<dim3(8, 512), 256, 0, stream>>>(
        (const float*)d_in[0], (const u16*)d_in[0], W1T,
        (const float*)d_in[2], (const u16*)d_in[2], proj, flag);

    if (use_pt) {
        transpose_bf16_kernel<<<dim3(16, 16, 64), 256, 0, stream>>>(proj, projT);
        attn_kernel<true><<<dim3(64, 64), 512, 0, stream>>>(
            proj, projT, W2T, (const float*)d_in[4], (const u16*)d_in[4],
            (float*)d_out, (u16*)d_out, flag);
    } else {
        attn_kernel<false><<<dim3(64, 64), 512, 0, stream>>>(
            proj, projT, W2T, (const float*)d_in[4], (const u16*)d_in[4],
            (float*)d_out, (u16*)d_out, flag);
    }
}

// Round 6
// 1535.970 us; speedup vs baseline: 1.7915x; 1.7915x over previous
//
#include <hip/hip_runtime.h>

typedef unsigned short u16;
typedef __attribute__((ext_vector_type(8))) short bf16x8;
typedef __attribute__((ext_vector_type(4))) float f32x4;

// ---- bf16 helpers (RNE) ----
__device__ inline float bf2f(u16 u) {
    unsigned v = ((unsigned)u) << 16;
    return __builtin_bit_cast(float, v);
}
__device__ inline u16 f2bf(float f) {
    unsigned u = __builtin_bit_cast(unsigned, f);
    u += 0x7fff + ((u >> 16) & 1);
    return (u16)(u >> 16);
}

// ============================================================
// Dtype detector (fp32 vs bf16 device buffers). flag=1 -> fp32.
// ============================================================
__global__ void detect_kernel(const u16* __restrict__ xr, int* __restrict__ flag) {
    __shared__ int red[4];
    const int t = threadIdx.x;
    int cnt = 0;
    for (int j = 0; j < 64; ++j) {
        u16 v = xr[(t * 64 + j) * 2];
        int e = (v >> 7) & 0xFF;
        cnt += (e >= 0x86);
    }
    for (int o = 32; o >= 1; o >>= 1) cnt += __shfl_xor(cnt, o);
    if ((t & 63) == 0) red[t >> 6] = cnt;
    __syncthreads();
    if (t == 0) flag[0] = ((red[0] + red[1] + red[2] + red[3]) > 1000) ? 1 : 0;
}

// ============================================================
// Weight transpose + convert-to-bf16: dst[C][R] = bf16(src[R][C])
// ============================================================
__global__ __launch_bounds__(256) void transpose_kernel(const float* __restrict__ srcf,
                                                        const u16* __restrict__ srch,
                                                        u16* __restrict__ dst,
                                                        int R, int C,
                                                        const int* __restrict__ flag) {
    __shared__ u16 tile[64][65];
    const bool isf32 = flag[0] != 0;
    const int t = threadIdx.x;
    const int c0 = blockIdx.x * 64, r0 = blockIdx.y * 64;
    const int lc = t & 63, lr4 = t >> 6;
#pragma unroll
    for (int i = 0; i < 16; ++i) {
        int row = i * 4 + lr4;
        size_t idx = (size_t)(r0 + row) * C + c0 + lc;
        tile[row][lc] = isf32 ? f2bf(srcf[idx]) : srch[idx];
    }
    __syncthreads();
#pragma unroll
    for (int i = 0; i < 16; ++i) {
        int drow = i * 4 + lr4;
        dst[(size_t)(c0 + drow) * R + r0 + lc] = tile[lc][drow];
    }
}

// ============================================================
// GEMM1: proj[65536][1024] = bf16(x)[65536][512] @ W1 + bias1, bf16 out
// ============================================================
__global__ __launch_bounds__(256) void gemm1_kernel(const float* __restrict__ xf,
                                                    const u16* __restrict__ xh,
                                                    const u16* __restrict__ w1t,
                                                    const float* __restrict__ b1f,
                                                    const u16* __restrict__ b1h,
                                                    u16* __restrict__ proj,
                                                    const int* __restrict__ flag) {
    __shared__ u16 Al[128 * 64];
    __shared__ u16 Bl[128 * 64];
    const bool isf32 = flag[0] != 0;
    const int t = threadIdx.x;
    const int lane = t & 63;
    const int w = t >> 6;
    const int r0 = blockIdx.y * 128;
    const int c0 = blockIdx.x * 128;
    const int wr = (w >> 1) * 64, wc = (w & 1) * 64;

    f32x4 acc[4][4] = {};

    for (int kt = 0; kt < 8; ++kt) {
        const int k0 = kt * 64;
#pragma unroll
        for (int i = 0; i < 4; ++i) {
            int c = i * 256 + t;
            int row = c >> 3;
            int off = (c & 7) * 8;
            size_t gidx = (size_t)(r0 + row) * 512 + k0 + off;
            bf16x8 av;
            if (isf32) {
                f32x4 f0 = *(const f32x4*)&xf[gidx];
                f32x4 f1 = *(const f32x4*)&xf[gidx + 4];
#pragma unroll
                for (int j = 0; j < 4; ++j) {
                    av[j] = (short)f2bf(f0[j]);
                    av[j + 4] = (short)f2bf(f1[j]);
                }
            } else {
                av = *(const bf16x8*)&xh[gidx];
            }
            *(bf16x8*)&Al[row * 64 + off] = av;
            *(bf16x8*)&Bl[row * 64 + off] =
                *(const bf16x8*)&w1t[(size_t)(c0 + row) * 512 + k0 + off];
        }
        __syncthreads();
#pragma unroll
        for (int kk = 0; kk < 64; kk += 32) {
            bf16x8 a[4], bb[4];
#pragma unroll
            for (int m = 0; m < 4; ++m)
                a[m] = *(const bf16x8*)&Al[(wr + m * 16 + (lane & 15)) * 64 + kk + (lane >> 4) * 8];
#pragma unroll
            for (int n = 0; n < 4; ++n)
                bb[n] = *(const bf16x8*)&Bl[(wc + n * 16 + (lane & 15)) * 64 + kk + (lane >> 4) * 8];
#pragma unroll
            for (int m = 0; m < 4; ++m)
#pragma unroll
                for (int n = 0; n < 4; ++n)
                    acc[m][n] = __builtin_amdgcn_mfma_f32_16x16x32_bf16(a[m], bb[n], acc[m][n], 0, 0, 0);
        }
        __syncthreads();
    }

#pragma unroll
    for (int n = 0; n < 4; ++n) {
        int col = c0 + wc + n * 16 + (lane & 15);
        float bv = isf32 ? b1f[col] : bf2f(b1h[col]);
#pragma unroll
        for (int m = 0; m < 4; ++m) {
            int rbase = r0 + wr + m * 16 + (lane >> 4) * 4;
#pragma unroll
            for (int i = 0; i < 4; ++i)
                proj[(size_t)(rbase + i) * 1024 + col] = f2bf(acc[m][n][i] + bv);
        }
    }
}

// ============================================================
// Fused attention per wg = (batch b, 32 query rows). 512 thr = 8 waves.
// Grid = 2048 linear wgs, XCD-pinned: wg linear id i -> xcd=i&7, batch
// b=(i>>8)*8+xcd (so all 32 wgs of batch b land on XCD b&7 and its 2 MB
// K/V slab stays L2-resident there), qtile q=(i>>3)&31.
// LDS = 64 KiB: P bf16 [32][1024] XOR-swizzled; mred/sred overlay its
// first 2 KiB (consumed before P write); O overlays it after PV.
// ============================================================
__global__ __launch_bounds__(512) void attn_kernel(const u16* __restrict__ proj,
                                                   const u16* __restrict__ w2t,
                                                   const float* __restrict__ b2f,
                                                   const u16* __restrict__ b2h,
                                                   float* __restrict__ outf,
                                                   u16* __restrict__ outh,
                                                   const int* __restrict__ flag) {
    __shared__ u16 Pl[32 * 1024];           // 65536 B exactly
    const bool isf32 = flag[0] != 0;
    const int t = threadIdx.x;
    const int lane = t & 63;
    const int w = t >> 6;
    const int i_wg = blockIdx.x;
    const int xcd = i_wg & 7;
    const int q = (i_wg >> 3) & 31;
    const int b = (i_wg >> 8) * 8 + xcd;
    const int n0 = q * 32;
    const u16* pb = proj + (size_t)b * 1024 * 1024;
    const int g = lane >> 4;
    const int lr = lane & 15;

    // ---- Phase 1: S = Q @ relu(K)^T / 32, in registers (2 rf x 8 cf frags)
    f32x4 acc[2][8] = {};
    const int mw = w * 128;
    for (int kk = 0; kk < 1024; kk += 32) {
        const int e = kk + g * 8;
        bf16x8 a[2];
#pragma unroll
        for (int rf = 0; rf < 2; ++rf)
            a[rf] = *(const bf16x8*)&pb[(size_t)(n0 + rf * 16 + lr) * 1024 + e];
        bf16x8 kf[8];
#pragma unroll
        for (int cf = 0; cf < 8; ++cf) {
            bf16x8 v = *(const bf16x8*)&pb[(size_t)(mw + cf * 16 + lr) * 1024 + e];
            v &= ~(v >> 15);   // bf16 relu
            kf[cf] = v;
        }
#pragma unroll
        for (int rf = 0; rf < 2; ++rf)
#pragma unroll
            for (int cf = 0; cf < 8; ++cf)
                acc[rf][cf] = __builtin_amdgcn_mfma_f32_16x16x32_bf16(a[rf], kf[cf], acc[rf][cf], 0, 0, 0);
    }
    {
        const float sc = 1.0f / 32.0f;
#pragma unroll
        for (int rf = 0; rf < 2; ++rf)
#pragma unroll
            for (int cf = 0; cf < 8; ++cf)
#pragma unroll
                for (int i = 0; i < 4; ++i) acc[rf][cf][i] *= sc;
    }

    // ---- Phase 2: softmax. Row ri = rf*16 + g*4 + i, cols across 16 lr x 8 cf.
    float* redm = (float*)Pl;          // [32][8] floats (1 KiB)
    float* reds = (float*)Pl + 256;    // [32][8] floats (1 KiB)
    {
#pragma unroll
        for (int rf = 0; rf < 2; ++rf)
#pragma unroll
            for (int i = 0; i < 4; ++i) {
                float m = acc[rf][0][i];
#pragma unroll
                for (int cf = 1; cf < 8; ++cf) m = fmaxf(m, acc[rf][cf][i]);
                for (int o = 8; o >= 1; o >>= 1) m = fmaxf(m, __shfl_xor(m, o));
                if (lr == 0) redm[(rf * 16 + g * 4 + i) * 8 + w] = m;
            }
    }
    __syncthreads();
    {
#pragma unroll
        for (int rf = 0; rf < 2; ++rf)
#pragma unroll
            for (int i = 0; i < 4; ++i) {
                int ri = rf * 16 + g * 4 + i;
                float m = redm[ri * 8 + 0];
#pragma unroll
                for (int w2 = 1; w2 < 8; ++w2) m = fmaxf(m, redm[ri * 8 + w2]);
                float s = 0.f;
#pragma unroll
                for (int cf = 0; cf < 8; ++cf) {
                    acc[rf][cf][i] = __expf(acc[rf][cf][i] - m);
                    s += acc[rf][cf][i];
                }
                for (int o = 8; o >= 1; o >>= 1) s += __shfl_xor(s, o);
                if (lr == 0) reds[ri * 8 + w] = s;
            }
    }
    __syncthreads();
    float inv[2][4];
    {
#pragma unroll
        for (int rf = 0; rf < 2; ++rf)
#pragma unroll
            for (int i = 0; i < 4; ++i) {
                int ri = rf * 16 + g * 4 + i;
                float s = reds[ri * 8 + 0];
#pragma unroll
                for (int w2 = 1; w2 < 8; ++w2) s += reds[ri * 8 + w2];
                inv[rf][i] = 1.0f / s;
            }
    }
    __syncthreads();   // everyone has read redm/reds -> safe to overwrite with P
    {
        char* Pb = (char*)Pl;
#pragma unroll
        for (int rf = 0; rf < 2; ++rf)
#pragma unroll
            for (int i = 0; i < 4; ++i) {
                int ri = rf * 16 + g * 4 + i;
                int rx = (ri & 7) << 4;
                char* prow = Pb + ri * 2048;
#pragma unroll
                for (int cf = 0; cf < 8; ++cf) {
                    int c = mw + cf * 16 + lr;
                    *(u16*)(prow + ((2 * c) ^ rx)) = f2bf(acc[rf][cf][i] * inv[rf][i]);
                }
            }
    }
    __syncthreads();

    // ---- Phase 3: O = P @ V ; V gathered from proj (L2-resident after swizzle).
    // vv is shared across both rf fragments -> gather count independent of QBLK.
    f32x4 acc2[2][8] = {};
    {
        const int ew = w * 128;
        const char* Pb = (const char*)Pl;
        for (int m0 = 0; m0 < 1024; m0 += 32) {
            const int mq = m0 + g * 8;
            bf16x8 pa[2];
#pragma unroll
            for (int rf = 0; rf < 2; ++rf) {
                int pr = rf * 16 + lr;
                pa[rf] = *(const bf16x8*)(Pb + pr * 2048 + ((2 * mq) ^ ((pr & 7) << 4)));
            }
#pragma unroll
            for (int cf = 0; cf < 8; ++cf) {
                const u16* vp = &pb[(size_t)mq * 1024 + ew + cf * 16 + lr];
                bf16x8 vv;
#pragma unroll
                for (int j = 0; j < 8; ++j) vv[j] = (short)vp[(size_t)j * 1024];
#pragma unroll
                for (int rf = 0; rf < 2; ++rf)
                    acc2[rf][cf] = __builtin_amdgcn_mfma_f32_16x16x32_bf16(pa[rf], vv, acc2[rf][cf], 0, 0, 0);
            }
        }
    }
    __syncthreads();   // all P reads done -> overlay O (XOR-swizzled, stride 1024)
    {
        const int ew = w * 128;
        char* Ob = (char*)Pl;
#pragma unroll
        for (int rf = 0; rf < 2; ++rf)
#pragma unroll
            for (int cf = 0; cf < 8; ++cf)
#pragma unroll
                for (int i = 0; i < 4; ++i) {
                    int orow = rf * 16 + g * 4 + i;
                    int rx = (orow & 7) << 4;
                    *(u16*)(Ob + orow * 2048 + ((2 * (ew + cf * 16 + lr)) ^ rx)) =
                        f2bf(acc2[rf][cf][i]);
                }
    }
    __syncthreads();

    // ---- Phase 4: out = relu(O @ W2 + bias2); wave owns 64 output cols
    {
        f32x4 acc3[2][4] = {};
        const int dw = w * 64;
        const char* Ob = (const char*)Pl;
        for (int kk = 0; kk < 1024; kk += 32) {
            const int e0 = kk + g * 8;
            bf16x8 oa[2];
#pragma unroll
            for (int rf = 0; rf < 2; ++rf) {
                int orow = rf * 16 + lr;
                oa[rf] = *(const bf16x8*)(Ob + orow * 2048 + ((2 * e0) ^ ((orow & 7) << 4)));
            }
            bf16x8 wb[4];
#pragma unroll
            for (int cf = 0; cf < 4; ++cf)
                wb[cf] = *(const bf16x8*)&w2t[(size_t)(dw + cf * 16 + lr) * 1024 + e0];
#pragma unroll
            for (int rf = 0; rf < 2; ++rf)
#pragma unroll
                for (int cf = 0; cf < 4; ++cf)
                    acc3[rf][cf] = __builtin_amdgcn_mfma_f32_16x16x32_bf16(oa[rf], wb[cf], acc3[rf][cf], 0, 0, 0);
        }
#pragma unroll
        for (int cf = 0; cf < 4; ++cf) {
            int d = dw + cf * 16 + lr;
            float bv = isf32 ? b2f[d] : bf2f(b2h[d]);
#pragma unroll
            for (int rf = 0; rf < 2; ++rf)
#pragma unroll
                for (int i = 0; i < 4; ++i) {
                    float v = fmaxf(acc3[rf][cf][i] + bv, 0.f);
                    size_t oi = ((size_t)b * 1024 + n0 + rf * 16 + g * 4 + i) * 512 + d;
                    if (isf32) outf[oi] = v;
                    else outh[oi] = f2bf(v);
                }
        }
    }
}

// ============================================================
// Launch. ws: [0,1MB) W1T | [1MB,2MB) W2T | [2MB,130MB) proj | flag @130MB
// ============================================================
extern "C" void kernel_launch(void* const* d_in, const int* in_sizes, int n_in,
                              void* d_out, int out_size, void* d_ws, size_t ws_size,
                              hipStream_t stream) {
    char* ws = (char*)d_ws;
    u16* W1T  = (u16*)ws;
    u16* W2T  = (u16*)(ws + (1u << 20));
    u16* proj = (u16*)(ws + (2u << 20));
    int* flag = (int*)(ws + ((size_t)130 << 20));

    detect_kernel<<<1, 256, 0, stream>>>((const u16*)d_in[0], flag);

    transpose_kernel<<<dim3(16, 8, 1), 256, 0, stream>>>(
        (const float*)d_in[1], (const u16*)d_in[1], W1T, 512, 1024, flag);
    transpose_kernel<<<dim3(8, 16, 1), 256, 0, stream>>>(
        (const float*)d_in[3], (const u16*)d_in[3], W2T, 1024, 512, flag);

    gemm1_kernel<<<dim3(8, 512), 256, 0, stream>>>(
        (const float*)d_in[0], (const u16*)d_in[0], W1T,
        (const float*)d_in[2], (const u16*)d_in[2], proj, flag);

    // fused attention + output projection: 2048 XCD-pinned wgs (32 qtiles x 64 b)
    attn_kernel<<<dim3(2048), 512, 0, stream>>>(
        proj, W2T, (const float*)d_in[4], (const u16*)d_in[4],
        (float*)d_out, (u16*)d_out, flag);
}